// Round 18
// baseline (285.336 us; speedup 1.0000x reference)
//
#include <hip/hip_runtime.h>
#include <math.h>

#define NQ    8192   // B*S
#define T3    48
#define INDIM 1024
#define HID   128
#define MSLOT 8192
#define HD    256
#define KBIG  48
#define KBASE 32
#define NSAMP 1024   // threshold sample = first 1024 columns
#define NTIL  32     // column tiles (256 cols each)
#define TCAP  48     // candidate slots per (row, tile)
#define RSTR  (NTIL * TCAP)   // 1536 slots per row
#define MROW  8      // row-groups (of 32 rows) per k2c block

// ---- workspace layout (bytes); ws = 256 MiB ----
#define OFF_QH    ((size_t)0)           // 8192*64 bf16
#define OFF_QL    ((size_t)1048576)
#define OFF_Q2    ((size_t)2097152)
#define OFF_M2    ((size_t)2129920)
#define OFF_CW    ((size_t)2162688)
#define OFF_TOPV  ((size_t)2195456)     // 8192*48 f32
#define OFF_TOPI  ((size_t)3768320)
#define OFF_RMIN  ((size_t)5341184)
#define OFF_FLAG  ((size_t)5373952)
#define OFF_WOT   ((size_t)5374208)     // 1024*256 bf16
#define OFF_PEH   ((size_t)5898496)     // 8192*64 bf16
#define OFF_PEL   ((size_t)6947072)
#define OFF_WPTH  ((size_t)7995648)     // 48*1024 bf16
#define OFF_WPTL  ((size_t)8093952)
#define OFF_H0    ((size_t)8192256)     // 8192*48 f32
#define OFF_RTHR  ((size_t)9765120)     // 8192 f32
#define OFF_ATTB  ((size_t)9830656)     // 8192*256 bf16
#define OFF_DISTS ((size_t)14024960)    // 8192*1024 f32 = 33.5MB
#define OFF_CANDS ((size_t)47579392)    // 8192*1536 u64 = 100.7MB
#define OFF_CNT2  ((size_t)150994944)   // 8192*32 i32 = 1MB
#define OFF_SLOTB ((size_t)152043520)   // 8192*256 bf16 = 4MB
// end < 256 MiB

typedef __attribute__((ext_vector_type(8))) short short8;
typedef __attribute__((ext_vector_type(4))) float f32x4;

__device__ __forceinline__ float gelu_exact(float x) {
    return 0.5f * x * (1.0f + erff(x * 0.70710678118654752f));
}

__device__ __forceinline__ unsigned short bf16_rne(float f) {
    unsigned int x = __float_as_uint(f);
    unsigned int r = (x + 0x7fffu + ((x >> 16) & 1u)) >> 16;
    return (unsigned short)r;
}

__device__ __forceinline__ void split2(float x, unsigned short& h, unsigned short& l) {
    h = bf16_rne(x);
    l = bf16_rne(x - __uint_as_float((unsigned)h << 16));
}

// ---- K0: m2, cw, pe hi/lo bf16 (K padded to 64) ----
__global__ __launch_bounds__(256) void k0_prep(const float* __restrict__ pe,
        const float* __restrict__ curv, const float* __restrict__ alpha,
        float* __restrict__ m2, float* __restrict__ cw,
        unsigned short* __restrict__ ph, unsigned short* __restrict__ pl) {
    int m = blockIdx.x * 256 + threadIdx.x;
    float s = 0.f;
    for (int d = 0; d < T3; d++) { float v = pe[(size_t)m * T3 + d]; s += v * v; }
    m2[m] = s;
    float c = 0.f;
    for (int d = 0; d < 16; d++) { float v = curv[m * 16 + d]; c += v * v; }
    cw[m] = expf(-alpha[0] * sqrtf(c));
    int base = blockIdx.x * 256;
    for (int idx = threadIdx.x; idx < 256 * 64; idx += 256) {
        int r = idx >> 6, cc = idx & 63;
        unsigned short hi = 0, lo = 0;
        if (cc < T3) split2(pe[(size_t)(base + r) * T3 + cc], hi, lo);
        size_t o = (size_t)(base + r) * 64 + cc;
        ph[o] = hi; pl[o] = lo;
    }
}

// ---- K0b: Wo_t[n][k] = bf16(Wo[k][n]) ----
__global__ __launch_bounds__(256) void k0b_cvt(const float* __restrict__ Wo,
        unsigned short* __restrict__ Wot) {
    __shared__ float t[64][65];
    int k0 = blockIdx.x * 64;
    int n0 = blockIdx.y * 64;
    int c = threadIdx.x & 63, r4 = threadIdx.x >> 6;
    #pragma unroll
    for (int i = 0; i < 16; i++) {
        int kr = i * 4 + r4;
        t[kr][c] = Wo[(size_t)(k0 + kr) * INDIM + n0 + c];
    }
    __syncthreads();
    #pragma unroll
    for (int i = 0; i < 16; i++) {
        int nr = i * 4 + r4;
        Wot[(size_t)(n0 + nr) * HD + k0 + c] = bf16_rne(t[c][nr]);
    }
}

// ---- K0d: WpT hi/lo: wpt[n][k] = Wp[k][n] ----
__global__ __launch_bounds__(256) void k0d_wpt(const float* __restrict__ Wp,
        unsigned short* __restrict__ wph, unsigned short* __restrict__ wpl) {
    int n = blockIdx.x;
    for (int k = threadIdx.x; k < INDIM; k += 256) {
        unsigned short h, l;
        split2(Wp[(size_t)k * T3 + n], h, l);
        wph[(size_t)n * INDIM + k] = h;
        wpl[(size_t)n * INDIM + k] = l;
    }
}

// ---- K0e: slots -> bf16 (4MB table, fits per-XCD L2) ----
__global__ __launch_bounds__(256) void k0e_slotb(const float* __restrict__ slots,
        unsigned short* __restrict__ sb) {
    size_t base = ((size_t)blockIdx.x * 256 + threadIdx.x) * 8;
    float4 a = *(const float4*)(slots + base);
    float4 b = *(const float4*)(slots + base + 4);
    unsigned short h[8];
    h[0] = bf16_rne(a.x); h[1] = bf16_rne(a.y); h[2] = bf16_rne(a.z); h[3] = bf16_rne(a.w);
    h[4] = bf16_rne(b.x); h[5] = bf16_rne(b.y); h[6] = bf16_rne(b.z); h[7] = bf16_rne(b.w);
    uint4 o;
    o.x = h[0] | ((unsigned)h[1] << 16); o.y = h[2] | ((unsigned)h[3] << 16);
    o.z = h[4] | ((unsigned)h[5] << 16); o.w = h[6] | ((unsigned)h[7] << 16);
    *(uint4*)(sb + base) = o;
}

// ---- K1: h0 = x @ Wp via hi/lo bf16 MFMA; 16 rows/block (512 blocks) ----
__global__ __launch_bounds__(256) void k1_mfma(const float* __restrict__ x,
        const unsigned short* __restrict__ wph, const unsigned short* __restrict__ wpl,
        float* __restrict__ h0) {
    __shared__ float part[4][16][48];
    int tid = threadIdx.x, lane = tid & 63, wv = tid >> 6;
    int r0 = blockIdx.x * 16;
    int lm = lane & 15, lk8 = (lane >> 4) * 8;
    f32x4 acc[3];
    #pragma unroll
    for (int j = 0; j < 3; j++) acc[j] = (f32x4)(0.f);
    int kw = wv * 256;
    for (int ks = 0; ks < 8; ks++) {
        int kofs = kw + ks * 32 + lk8;
        short8 ah, al, bh[3], bl[3];
        {
            const float* xp = x + (size_t)(r0 + lm) * INDIM + kofs;
            float4 xa = *(const float4*)xp;
            float4 xb = *(const float4*)(xp + 4);
            float va[8] = {xa.x, xa.y, xa.z, xa.w, xb.x, xb.y, xb.z, xb.w};
            #pragma unroll
            for (int e = 0; e < 8; e++) {
                unsigned short h, l;
                split2(va[e], h, l);
                ah[e] = (short)h; al[e] = (short)l;
            }
        }
        #pragma unroll
        for (int j = 0; j < 3; j++) {
            size_t bo = (size_t)(j * 16 + lm) * INDIM + kofs;
            bh[j] = *(const short8*)(wph + bo);
            bl[j] = *(const short8*)(wpl + bo);
        }
        #pragma unroll
        for (int j = 0; j < 3; j++) {
            f32x4 a = acc[j];
            a = __builtin_amdgcn_mfma_f32_16x16x32_bf16(ah, bh[j], a, 0, 0, 0);
            a = __builtin_amdgcn_mfma_f32_16x16x32_bf16(ah, bl[j], a, 0, 0, 0);
            a = __builtin_amdgcn_mfma_f32_16x16x32_bf16(al, bh[j], a, 0, 0, 0);
            acc[j] = a;
        }
    }
    int orow = (lane >> 4) * 4;
    #pragma unroll
    for (int j = 0; j < 3; j++)
        #pragma unroll
        for (int r = 0; r < 4; r++)
            part[wv][orow + r][j * 16 + lm] = acc[j][r];
    __syncthreads();
    for (int idx = tid; idx < 16 * 48; idx += 256) {
        int rr = idx / 48, cc = idx - rr * 48;
        float s = part[0][rr][cc] + part[1][rr][cc] + part[2][rr][cc] + part[3][rr][cc];
        h0[(size_t)(r0 + rr) * T3 + cc] = s;
    }
}

// ---- K1b: 16 rows/block: bias + LN + GELU + 2 ODE steps -> qh/ql/q2 ----
__global__ __launch_bounds__(256) void k1b_ode(const float* __restrict__ h0,
        const float* __restrict__ bp,
        const float* __restrict__ g1, const float* __restrict__ b1ln,
        const float* __restrict__ W1, const float* __restrict__ bb1,
        const float* __restrict__ W2, const float* __restrict__ bb2,
        unsigned short* __restrict__ qh, unsigned short* __restrict__ ql,
        float* __restrict__ q2out) {
    __shared__ __align__(16) float W1s[T3 * HID];
    __shared__ __align__(16) float W2s[HID * T3];
    __shared__ __align__(16) float hs[16 * T3];
    __shared__ __align__(16) float t1s[16 * 132];
    int tid = threadIdx.x;
    size_t base = (size_t)blockIdx.x * 16 * T3;
    for (int i = tid; i < 1536; i += 256) {
        *(float4*)&W1s[i * 4] = *(const float4*)&W1[i * 4];
        *(float4*)&W2s[i * 4] = *(const float4*)&W2[i * 4];
    }
    for (int idx = tid; idx < 16 * T3; idx += 256) {
        int c = idx % T3;
        t1s[idx] = bp[c] + h0[base + idx];
    }
    __syncthreads();
    {
        int r = tid >> 4, c16 = tid & 15;
        float v[3];
        float ssum = 0.f;
        #pragma unroll
        for (int i = 0; i < 3; i++) { v[i] = t1s[r * T3 + c16 * 3 + i]; ssum += v[i]; }
        #pragma unroll
        for (int off = 1; off < 16; off <<= 1) ssum += __shfl_xor(ssum, off);
        float mean = ssum * (1.f / T3);
        float vv = 0.f;
        #pragma unroll
        for (int i = 0; i < 3; i++) { v[i] -= mean; vv += v[i] * v[i]; }
        #pragma unroll
        for (int off = 1; off < 16; off <<= 1) vv += __shfl_xor(vv, off);
        float rstd = rsqrtf(vv * (1.f / T3) + 1e-5f);
        #pragma unroll
        for (int i = 0; i < 3; i++) {
            int c = c16 * 3 + i;
            hs[r * T3 + c] = gelu_exact(v[i] * rstd * g1[c] + b1ln[c]);
        }
    }
    __syncthreads();
    for (int step = 0; step < 2; step++) {
        #pragma unroll
        for (int it = 0; it < 2; it++) {
            int idx = tid + it * 256;
            int rr = idx >> 5, j4 = idx & 31;
            float4 a = *(const float4*)&bb1[j4 * 4];
            #pragma unroll 3
            for (int d4 = 0; d4 < 12; d4++) {
                float4 qv = *(const float4*)&hs[rr * T3 + d4 * 4];
                float qa[4] = {qv.x, qv.y, qv.z, qv.w};
                #pragma unroll
                for (int dd = 0; dd < 4; dd++) {
                    float4 wv = *(const float4*)&W1s[(d4 * 4 + dd) * HID + j4 * 4];
                    a.x += qa[dd] * wv.x; a.y += qa[dd] * wv.y;
                    a.z += qa[dd] * wv.z; a.w += qa[dd] * wv.w;
                }
            }
            a.x = tanhf(a.x); a.y = tanhf(a.y); a.z = tanhf(a.z); a.w = tanhf(a.w);
            *(float4*)&t1s[rr * 132 + j4 * 4] = a;
        }
        __syncthreads();
        if (tid < 192) {
            int rr = tid / 12, c4 = tid % 12;
            float4 a = *(const float4*)&bb2[c4 * 4];
            #pragma unroll 4
            for (int j4 = 0; j4 < 32; j4++) {
                float4 tv = *(const float4*)&t1s[rr * 132 + j4 * 4];
                float ta[4] = {tv.x, tv.y, tv.z, tv.w};
                #pragma unroll
                for (int jj = 0; jj < 4; jj++) {
                    float4 wv = *(const float4*)&W2s[(j4 * 4 + jj) * T3 + c4 * 4];
                    a.x += ta[jj] * wv.x; a.y += ta[jj] * wv.y;
                    a.z += ta[jj] * wv.z; a.w += ta[jj] * wv.w;
                }
            }
            float4 cur = *(const float4*)&hs[rr * T3 + c4 * 4];
            cur.x += 0.5f * a.x; cur.y += 0.5f * a.y;
            cur.z += 0.5f * a.z; cur.w += 0.5f * a.w;
            *(float4*)&hs[rr * T3 + c4 * 4] = cur;
        }
        __syncthreads();
    }
    {
        int r = tid >> 4, c16 = tid & 15;
        float sq = 0.f;
        #pragma unroll
        for (int i = 0; i < 3; i++) { float v = hs[r * T3 + c16 * 3 + i]; sq += v * v; }
        #pragma unroll
        for (int off = 1; off < 16; off <<= 1) sq += __shfl_xor(sq, off);
        if (c16 == 0) q2out[(size_t)blockIdx.x * 16 + r] = sq;
    }
    for (int idx = tid; idx < 16 * 64; idx += 256) {
        int r = idx >> 6, c = idx & 63;
        unsigned short hi = 0, lo = 0;
        if (c < T3) split2(hs[r * T3 + c], hi, lo);
        size_t o = ((size_t)blockIdx.x * 16 + r) * 64 + c;
        qh[o] = hi; ql[o] = lo;
    }
}

// ---- K2a: sample dist; 32 rows/block; pl/bq loads hoisted before barrier ----
#define PES 72
__global__ __launch_bounds__(256, 4) void k2a_mfma(
        const unsigned short* __restrict__ qh, const unsigned short* __restrict__ ql,
        const float* __restrict__ q2g,
        const unsigned short* __restrict__ ph, const unsigned short* __restrict__ pl,
        const float* __restrict__ m2, const float* __restrict__ cw,
        float* __restrict__ dist, int rowstride) {
    __shared__ __align__(16) char smem[256 * PES * 2];
    __shared__ float q2s[32];
    unsigned short* pesh = (unsigned short*)smem;
    int tid = threadIdx.x, lane = tid & 63, wv = tid >> 6;
    int c0 = blockIdx.x * 256;
    int grow0 = blockIdx.y * 32;
    for (int idx = tid; idx < 2048; idx += 256) {
        int col = idx >> 3, ch = idx & 7;
        *(uint4*)&pesh[col * PES + ch * 8] = *(const uint4*)&ph[(size_t)(c0 + col) * 64 + ch * 8];
    }
    if (tid < 32) q2s[tid] = q2g[grow0 + tid];
    int lm = lane & 15, lk8 = (lane >> 4) * 8;
    int mco = wv * 64;
    short8 bqh[2][2], bql[2][2];
    #pragma unroll
    for (int qs = 0; qs < 2; qs++)
        #pragma unroll
        for (int ks = 0; ks < 2; ks++) {
            size_t o = (size_t)(grow0 + qs * 16 + lm) * 64 + ks * 32 + lk8;
            bqh[qs][ks] = *(const short8*)&qh[o];
            bql[qs][ks] = *(const short8*)&ql[o];
        }
    short8 al0[4], al1[4];
    #pragma unroll
    for (int ms = 0; ms < 4; ms++) {
        size_t plo = (size_t)(c0 + mco + ms * 16 + lm) * 64;
        al0[ms] = *(const short8*)&pl[plo + lk8];
        al1[ms] = *(const short8*)&pl[plo + 32 + lk8];
    }
    __syncthreads();
    f32x4 acc[4][2];
    #pragma unroll
    for (int i = 0; i < 4; i++)
        #pragma unroll
        for (int j = 0; j < 2; j++) acc[i][j] = (f32x4)(0.f);
    #pragma unroll
    for (int ms = 0; ms < 4; ms++) {
        int arow = mco + ms * 16 + lm;
        short8 ah0 = *(const short8*)&pesh[arow * PES + lk8];
        short8 ah1 = *(const short8*)&pesh[arow * PES + 32 + lk8];
        #pragma unroll
        for (int qs = 0; qs < 2; qs++) {
            f32x4 a = acc[ms][qs];
            a = __builtin_amdgcn_mfma_f32_16x16x32_bf16(ah0, bqh[qs][0], a, 0, 0, 0);
            a = __builtin_amdgcn_mfma_f32_16x16x32_bf16(ah1, bqh[qs][1], a, 0, 0, 0);
            a = __builtin_amdgcn_mfma_f32_16x16x32_bf16(ah0, bql[qs][0], a, 0, 0, 0);
            a = __builtin_amdgcn_mfma_f32_16x16x32_bf16(ah1, bql[qs][1], a, 0, 0, 0);
            a = __builtin_amdgcn_mfma_f32_16x16x32_bf16(al0[ms], bqh[qs][0], a, 0, 0, 0);
            a = __builtin_amdgcn_mfma_f32_16x16x32_bf16(al1[ms], bqh[qs][1], a, 0, 0, 0);
            acc[ms][qs] = a;
        }
    }
    int mr4 = (lane >> 4) * 4;
    #pragma unroll
    for (int ms = 0; ms < 4; ms++) {
        int gm = c0 + mco + ms * 16 + mr4;
        float4 m2v = *(const float4*)&m2[gm];
        float4 cwv = *(const float4*)&cw[gm];
        float m2a[4] = {m2v.x, m2v.y, m2v.z, m2v.w};
        float cwa[4] = {cwv.x, cwv.y, cwv.z, cwv.w};
        #pragma unroll
        for (int qs = 0; qs < 2; qs++) {
            float q2 = q2s[qs * 16 + lm];
            #pragma unroll
            for (int c = 0; c < 4; c++)
                acc[ms][qs][c] = fmaxf(q2 + m2a[c] - 2.f * acc[ms][qs][c], 0.f) * cwa[c];
        }
    }
    __syncthreads();
    float (*dt)[260] = (float(*)[260])smem;
    #pragma unroll
    for (int ms = 0; ms < 4; ms++)
        #pragma unroll
        for (int qs = 0; qs < 2; qs++) {
            float4 o;
            o.x = acc[ms][qs][0]; o.y = acc[ms][qs][1];
            o.z = acc[ms][qs][2]; o.w = acc[ms][qs][3];
            *(float4*)&dt[qs * 16 + lm][mco + ms * 16 + mr4] = o;
        }
    __syncthreads();
    #pragma unroll
    for (int i = 0; i < 8; i++) {
        int qrow = wv * 8 + i;
        float4 v = *(const float4*)&dt[qrow][lane * 4];
        *(float4*)&dist[(size_t)(grow0 + qrow) * rowstride + c0 + lane * 4] = v;
    }
}

// ---- K2b_thr: exact 48th-smallest of the NSAMP sample -> rowthr ----
#define NBINT 2048
#define MAXCT 512
__global__ __launch_bounds__(256) void k2b_thr(const float* __restrict__ dists,
        float* __restrict__ rowthr) {
    __shared__ unsigned int hist[NBINT];
    __shared__ unsigned long long cand[MAXCT];
    __shared__ float s_wmin[4], s_wmax[4];
    __shared__ unsigned int wsum[4];
    __shared__ unsigned int s_B, s_ncand;
    int tid = threadIdx.x, lane = tid & 63, wv = tid >> 6;
    int row = blockIdx.x;
    float4 v4 = *(const float4*)(dists + (size_t)row * NSAMP + tid * 4);
    float fv[4] = {v4.x, v4.y, v4.z, v4.w};
    float mn = fminf(fminf(fv[0], fv[1]), fminf(fv[2], fv[3]));
    float mx = fmaxf(fmaxf(fv[0], fv[1]), fmaxf(fv[2], fv[3]));
    #pragma unroll
    for (int off = 32; off; off >>= 1) {
        mn = fminf(mn, __shfl_xor(mn, off));
        mx = fmaxf(mx, __shfl_xor(mx, off));
    }
    if (lane == 0) { s_wmin[wv] = mn; s_wmax[wv] = mx; }
    __syncthreads();
    float m0 = fminf(fminf(s_wmin[0], s_wmin[1]), fminf(s_wmin[2], s_wmin[3]));
    float mX = fmaxf(fmaxf(s_wmax[0], s_wmax[1]), fmaxf(s_wmax[2], s_wmax[3]));
    float lo = m0;
    float width = fmaxf(m0 * 0.5f, 1e-3f);
    float fullw = fmaxf((mX - m0) * 1.0001f, 1e-3f) + 1e-6f;
    unsigned B = 0;
    float scale = 0.f, hiT = 0.f;
    for (int att = 0; att < 7; att++) {
        if (att == 6 || width > fullw) width = fullw;
        hiT = lo + width;
        scale = (float)NBINT / width;
        for (int i = tid; i < NBINT; i += 256) hist[i] = 0;
        __syncthreads();
        #pragma unroll
        for (int j = 0; j < 4; j++) {
            float v = fv[j];
            if (v < hiT) {
                int b = (int)((v - lo) * scale);
                b = b < NBINT - 1 ? b : NBINT - 1;
                atomicAdd(&hist[b], 1u);
            }
        }
        __syncthreads();
        unsigned hb[8];
        unsigned s = 0;
        #pragma unroll
        for (int i = 0; i < 8; i++) { hb[i] = hist[tid * 8 + i]; s += hb[i]; }
        unsigned v = s;
        #pragma unroll
        for (int off = 1; off < 64; off <<= 1) {
            unsigned o = __shfl_up(v, off);
            if (lane >= off) v += o;
        }
        if (lane == 63) wsum[wv] = v;
        __syncthreads();
        unsigned wbase = 0;
        for (int w = 0; w < wv; w++) wbase += wsum[w];
        unsigned total = wsum[0] + wsum[1] + wsum[2] + wsum[3];
        if (total >= KBIG) {
            unsigned excl = wbase + v - s;
            if (excl < KBIG && KBIG <= excl + s) {
                unsigned c = excl;
                #pragma unroll
                for (int i = 0; i < 8; i++) {
                    if (c < KBIG && KBIG <= c + hb[i]) { s_B = tid * 8 + i; break; }
                    c += hb[i];
                }
            }
            __syncthreads();
            B = s_B;
            break;
        }
        width *= 8.f;
        __syncthreads();
    }
    if (tid == 0) s_ncand = 0;
    __syncthreads();
    #pragma unroll
    for (int j = 0; j < 4; j++) {
        float v = fv[j];
        if (v < hiT) {
            int b = (int)((v - lo) * scale);
            b = b < NBINT - 1 ? b : NBINT - 1;
            if ((unsigned)b <= B) {
                unsigned n = atomicAdd(&s_ncand, 1u);
                if (n < MAXCT)
                    cand[n] = ((unsigned long long)__float_as_uint(v) << 32)
                              | (unsigned)(tid * 4 + j);
            }
        }
    }
    __syncthreads();
    int nc = (int)(s_ncand < MAXCT ? s_ncand : MAXCT);
    for (int i = tid; i < nc; i += 256) {
        unsigned long long me = cand[i];
        int rank = 0;
        for (int j = 0; j < nc; j++) rank += (cand[j] < me) ? 1 : 0;
        if (rank == KBIG - 1)
            rowthr[row] = __uint_as_float((unsigned)(me >> 32));
    }
}

// ---- K2c v6: 8 row-groups per staged tile; amortized staging/pl loads ----
__global__ __launch_bounds__(256, 3) void k2c_filter(
        const unsigned short* __restrict__ qh, const unsigned short* __restrict__ ql,
        const float* __restrict__ q2g,
        const unsigned short* __restrict__ ph, const unsigned short* __restrict__ pl,
        const float* __restrict__ m2, const float* __restrict__ cw,
        const float* __restrict__ rowthr, int* __restrict__ cnt2,
        unsigned long long* __restrict__ cands) {
    __shared__ __align__(16) unsigned short pesh[256 * PES];     // 36,864B
    __shared__ unsigned long long lbuf[32][TCAP];                // 12,288B
    __shared__ float q2a[256];
    __shared__ float thra[256];
    __shared__ unsigned int lcnt[32];
    int tid = threadIdx.x, lane = tid & 63, wv = tid >> 6;
    int tile = blockIdx.x;
    int c0 = tile * 256;
    int rb0 = blockIdx.y * 256;
    for (int idx = tid; idx < 2048; idx += 256) {
        int col = idx >> 3, ch = idx & 7;
        *(uint4*)&pesh[col * PES + ch * 8] = *(const uint4*)&ph[(size_t)(c0 + col) * 64 + ch * 8];
    }
    q2a[tid] = q2g[rb0 + tid];
    thra[tid] = rowthr[rb0 + tid];
    int lm = lane & 15, lk8 = (lane >> 4) * 8;
    int mco = wv * 64;
    short8 al0[4], al1[4];
    #pragma unroll
    for (int ms = 0; ms < 4; ms++) {
        size_t plo = (size_t)(c0 + mco + ms * 16 + lm) * 64;
        al0[ms] = *(const short8*)&pl[plo + lk8];
        al1[ms] = *(const short8*)&pl[plo + 32 + lk8];
    }
    int mr4 = (lane >> 4) * 4;
    float m2a[4][4], cwa[4][4];
    #pragma unroll
    for (int ms = 0; ms < 4; ms++) {
        int gm = c0 + mco + ms * 16 + mr4;
        float4 m2v = *(const float4*)&m2[gm];
        float4 cwv = *(const float4*)&cw[gm];
        m2a[ms][0] = m2v.x; m2a[ms][1] = m2v.y; m2a[ms][2] = m2v.z; m2a[ms][3] = m2v.w;
        cwa[ms][0] = cwv.x; cwa[ms][1] = cwv.y; cwa[ms][2] = cwv.z; cwa[ms][3] = cwv.w;
    }
    for (int g = 0; g < MROW; g++) {
        int grow0 = rb0 + g * 32;
        short8 bqh[2][2], bql[2][2];
        #pragma unroll
        for (int qs = 0; qs < 2; qs++)
            #pragma unroll
            for (int ks = 0; ks < 2; ks++) {
                size_t o = (size_t)(grow0 + qs * 16 + lm) * 64 + ks * 32 + lk8;
                bqh[qs][ks] = *(const short8*)&qh[o];
                bql[qs][ks] = *(const short8*)&ql[o];
            }
        if (tid < 32) lcnt[tid] = 0;
        __syncthreads();
        f32x4 acc[4][2];
        #pragma unroll
        for (int i = 0; i < 4; i++)
            #pragma unroll
            for (int j = 0; j < 2; j++) acc[i][j] = (f32x4)(0.f);
        #pragma unroll
        for (int ms = 0; ms < 4; ms++) {
            int arow = mco + ms * 16 + lm;
            short8 ah0 = *(const short8*)&pesh[arow * PES + lk8];
            short8 ah1 = *(const short8*)&pesh[arow * PES + 32 + lk8];
            #pragma unroll
            for (int qs = 0; qs < 2; qs++) {
                f32x4 a = acc[ms][qs];
                a = __builtin_amdgcn_mfma_f32_16x16x32_bf16(ah0, bqh[qs][0], a, 0, 0, 0);
                a = __builtin_amdgcn_mfma_f32_16x16x32_bf16(ah1, bqh[qs][1], a, 0, 0, 0);
                a = __builtin_amdgcn_mfma_f32_16x16x32_bf16(ah0, bql[qs][0], a, 0, 0, 0);
                a = __builtin_amdgcn_mfma_f32_16x16x32_bf16(ah1, bql[qs][1], a, 0, 0, 0);
                a = __builtin_amdgcn_mfma_f32_16x16x32_bf16(al0[ms], bqh[qs][0], a, 0, 0, 0);
                a = __builtin_amdgcn_mfma_f32_16x16x32_bf16(al1[ms], bqh[qs][1], a, 0, 0, 0);
                acc[ms][qs] = a;
            }
        }
        #pragma unroll
        for (int ms = 0; ms < 4; ms++) {
            int gm = c0 + mco + ms * 16 + mr4;
            #pragma unroll
            for (int qs = 0; qs < 2; qs++) {
                int q = qs * 16 + lm;
                float q2 = q2a[g * 32 + q];
                float thr = thra[g * 32 + q];
                #pragma unroll
                for (int c = 0; c < 4; c++) {
                    float v = fmaxf(q2 + m2a[ms][c] - 2.f * acc[ms][qs][c], 0.f) * cwa[ms][c];
                    if (v <= thr) {
                        unsigned slot = atomicAdd(&lcnt[q], 1u);
                        if (slot < TCAP)
                            lbuf[q][slot] = ((unsigned long long)__float_as_uint(v) << 32)
                                            | (unsigned)(gm + c);
                    }
                }
            }
        }
        __syncthreads();
        if (tid < 32) {
            unsigned k = lcnt[tid];
            k = k < TCAP ? k : TCAP;
            lcnt[tid] = k;
            cnt2[(size_t)(grow0 + tid) * NTIL + tile] = (int)k;
        }
        __syncthreads();
        for (int idx = tid; idx < 32 * TCAP; idx += 256) {
            int q = idx / TCAP, i = idx - q * TCAP;
            if (i < (int)lcnt[q])
                cands[(size_t)(grow0 + q) * RSTR + tile * TCAP + i] = lbuf[q][i];
        }
    }
}

// ---- K2d v4: prefix-scan compaction -> histogram prefilter -> tiny rank ----
#define NBIND 2048
#define FINCAP 512
#define CLCAP (NTIL * TCAP)   // 1536
__global__ __launch_bounds__(256) void k2d_select(
        const unsigned long long* __restrict__ cands, const int* __restrict__ cnt2,
        float* __restrict__ topv, int* __restrict__ topi, float* __restrict__ rowmin) {
    __shared__ unsigned long long cl[CLCAP];     // 12KB
    __shared__ unsigned int hist[NBIND];         // 8KB
    __shared__ unsigned long long fin[FINCAP];   // 4KB
    __shared__ int cnt2s[NTIL];
    __shared__ int offs[NTIL];
    __shared__ int s_nc;
    __shared__ float s_mn[4], s_mx[4];
    __shared__ unsigned int wsum[4];
    __shared__ unsigned int s_B, s_nfin;
    int tid = threadIdx.x, lane = tid & 63, wv = tid >> 6;
    size_t row = blockIdx.x;
    if (tid < NTIL) cnt2s[tid] = cnt2[row * NTIL + tid];
    for (int i = tid; i < NBIND; i += 256) hist[i] = 0;
    if (tid == 0) s_nfin = 0;
    __syncthreads();
    if (tid < 64) {
        int v = (lane < NTIL) ? cnt2s[lane] : 0;
        #pragma unroll
        for (int off = 1; off < 32; off <<= 1) {
            int o = __shfl_up(v, off);
            if (lane >= off) v += o;
        }
        if (lane < NTIL) offs[lane] = v - cnt2s[lane];
        if (lane == NTIL - 1) s_nc = v;
    }
    __syncthreads();
    int nc = s_nc;
    for (int idx = tid; idx < CLCAP; idx += 256) {
        int t = idx / TCAP, i = idx - t * TCAP;
        if (i < cnt2s[t]) cl[offs[t] + i] = cands[row * RSTR + idx];
    }
    __syncthreads();
    float mn = 3.4e38f, mx = -3.4e38f;
    for (int i = tid; i < nc; i += 256) {
        float v = __uint_as_float((unsigned)(cl[i] >> 32));
        mn = fminf(mn, v); mx = fmaxf(mx, v);
    }
    #pragma unroll
    for (int off = 32; off; off >>= 1) {
        mn = fminf(mn, __shfl_xor(mn, off));
        mx = fmaxf(mx, __shfl_xor(mx, off));
    }
    if (lane == 0) { s_mn[wv] = mn; s_mx[wv] = mx; }
    __syncthreads();
    float m0 = fminf(fminf(s_mn[0], s_mn[1]), fminf(s_mn[2], s_mn[3]));
    float mX = fmaxf(fmaxf(s_mx[0], s_mx[1]), fmaxf(s_mx[2], s_mx[3]));
    float width = fmaxf((mX - m0) * 1.0001f, 1e-9f) + 1e-12f;
    float scale = (float)NBIND / width;
    for (int i = tid; i < nc; i += 256) {
        float v = __uint_as_float((unsigned)(cl[i] >> 32));
        int b = (int)((v - m0) * scale);
        b = b < NBIND - 1 ? b : NBIND - 1;
        atomicAdd(&hist[b], 1u);
    }
    __syncthreads();
    {
        unsigned hb[8];
        unsigned s = 0;
        #pragma unroll
        for (int i = 0; i < 8; i++) { hb[i] = hist[tid * 8 + i]; s += hb[i]; }
        unsigned v = s;
        #pragma unroll
        for (int off = 1; off < 64; off <<= 1) {
            unsigned o = __shfl_up(v, off);
            if (lane >= off) v += o;
        }
        if (lane == 63) wsum[wv] = v;
        __syncthreads();
        unsigned wbase = 0;
        for (int w = 0; w < wv; w++) wbase += wsum[w];
        unsigned excl = wbase + v - s;
        unsigned tgt = (unsigned)(nc < KBIG ? nc : KBIG);
        if (excl < tgt && tgt <= excl + s) {
            unsigned c = excl;
            #pragma unroll
            for (int i = 0; i < 8; i++) {
                if (c < tgt && tgt <= c + hb[i]) { s_B = tid * 8 + i; break; }
                c += hb[i];
            }
        }
        __syncthreads();
    }
    unsigned B = s_B;
    for (int i = tid; i < nc; i += 256) {
        float v = __uint_as_float((unsigned)(cl[i] >> 32));
        int b = (int)((v - m0) * scale);
        b = b < NBIND - 1 ? b : NBIND - 1;
        if ((unsigned)b <= B) {
            unsigned n = atomicAdd(&s_nfin, 1u);
            if (n < FINCAP) fin[n] = cl[i];
        }
    }
    __syncthreads();
    int nf = (int)s_nfin;
    if (nf <= FINCAP) {
        for (int i = tid; i < nf; i += 256) {
            unsigned long long me = fin[i];
            int rank = 0;
            for (int j = 0; j < nf; j++) rank += (fin[j] < me) ? 1 : 0;
            if (rank < KBIG) {
                float v = __uint_as_float((unsigned)(me >> 32));
                topv[row * KBIG + rank] = v;
                topi[row * KBIG + rank] = (int)(me & 0xFFFFFFFFu);
                if (rank == 0) rowmin[row] = v;
            }
        }
    } else {
        for (int i = tid; i < nc; i += 256) {
            unsigned long long me = cl[i];
            int rank = 0;
            for (int j = 0; j < nc; j++) rank += (cl[j] < me) ? 1 : 0;
            if (rank < KBIG) {
                float v = __uint_as_float((unsigned)(me >> 32));
                topv[row * KBIG + rank] = v;
                topi[row * KBIG + rank] = (int)(me & 0xFFFFFFFFu);
                if (rank == 0) rowmin[row] = v;
            }
        }
    }
}

// ---- K3a: fire flag ----
__global__ __launch_bounds__(256) void k3a_flag(const float* __restrict__ rowmin,
        int* __restrict__ flag) {
    __shared__ float red[256];
    int tid = threadIdx.x;
    float s = 0.f;
    for (int j = 0; j < NQ / 256; j++) s += rowmin[tid + 256 * j];
    red[tid] = s;
    __syncthreads();
    for (int st = 128; st; st >>= 1) {
        if (tid < st) red[tid] += red[tid + st];
        __syncthreads();
    }
    if (tid == 0) {
        float top1 = red[0] / (float)NQ;
        flag[0] = (top1 < 0.7f) ? 1 : 0;
    }
}

// ---- K3 v3: wave per row; bf16 slot gathers (512B/row) ----
__global__ __launch_bounds__(256) void k3_attend(const float* __restrict__ topv,
        const int* __restrict__ topi, const int* __restrict__ flag,
        const unsigned short* __restrict__ slotb, unsigned short* __restrict__ attb) {
    int tid = threadIdx.x;
    int lane = tid & 63, wv = tid >> 6;
    size_t row = (size_t)blockIdx.x * 4 + wv;
    int kc = flag[0] ? KBIG : KBASE;
    float v0 = topv[row * KBIG];
    float ev = 0.f;
    int mi = 0;
    if (lane < KBIG) {
        float v = topv[row * KBIG + lane];
        ev = (lane < kc) ? expf(-(v - v0)) : 0.f;
        mi = topi[row * KBIG + lane];
    }
    float ssum = ev;
    #pragma unroll
    for (int off = 32; off; off >>= 1) ssum += __shfl_xor(ssum, off);
    float inv = 1.f / ssum;
    float4 acc = make_float4(0.f, 0.f, 0.f, 0.f);
    for (int k = 0; k < kc; k++) {
        float wk = __shfl(ev, k) * inv;
        int m = __shfl(mi, k);
        ushort4 sv = *(const ushort4*)(slotb + (size_t)m * HD + lane * 4);
        acc.x += wk * __uint_as_float((unsigned)sv.x << 16);
        acc.y += wk * __uint_as_float((unsigned)sv.y << 16);
        acc.z += wk * __uint_as_float((unsigned)sv.z << 16);
        acc.w += wk * __uint_as_float((unsigned)sv.w << 16);
    }
    ushort4 o;
    o.x = bf16_rne(acc.x); o.y = bf16_rne(acc.y);
    o.z = bf16_rne(acc.z); o.w = bf16_rne(acc.w);
    *(ushort4*)(attb + row * HD + lane * 4) = o;
}

// ---- K4: out = att(bf16) @ Wo_t(bf16)^T + bo via MFMA ----
__global__ __launch_bounds__(256) void k4_mfma(const unsigned short* __restrict__ A,
        const unsigned short* __restrict__ Bt, const float* __restrict__ bo,
        float* __restrict__ out) {
    int tid = threadIdx.x;
    int lane = tid & 63, wave = tid >> 6;
    int wm = wave >> 1, wn = wave & 1;
    int mbase = blockIdx.y * 128 + wm * 64;
    int nbase = blockIdx.x * 128 + wn * 64;
    int lm = lane & 15;
    int lk8 = (lane >> 4) * 8;
    f32x4 acc[4][4];
    #pragma unroll
    for (int i = 0; i < 4; i++)
        #pragma unroll
        for (int j = 0; j < 4; j++) acc[i][j] = (f32x4)(0.f);
    #pragma unroll 2
    for (int ks = 0; ks < 8; ks++) {
        int kofs = ks * 32 + lk8;
        short8 a[4], b[4];
        #pragma unroll
        for (int i = 0; i < 4; i++)
            a[i] = *(const short8*)(A + (size_t)(mbase + i * 16 + lm) * HD + kofs);
        #pragma unroll
        for (int j = 0; j < 4; j++)
            b[j] = *(const short8*)(Bt + (size_t)(nbase + j * 16 + lm) * HD + kofs);
        #pragma unroll
        for (int i = 0; i < 4; i++)
            #pragma unroll
            for (int j = 0; j < 4; j++)
                acc[i][j] = __builtin_amdgcn_mfma_f32_16x16x32_bf16(a[i], b[j], acc[i][j], 0, 0, 0);
    }
    int orow = (lane >> 4) * 4;
    #pragma unroll
    for (int i = 0; i < 4; i++)
        #pragma unroll
        for (int j = 0; j < 4; j++) {
            int col = nbase + j * 16 + lm;
            float bias = bo[col];
            #pragma unroll
            for (int r = 0; r < 4; r++) {
                int row = mbase + i * 16 + orow + r;
                out[(size_t)row * INDIM + col] = acc[i][j][r] + bias;
            }
        }
}

// ---- K5: LN + GELU in place ----
__global__ __launch_bounds__(256) void k5_ln(float* __restrict__ out,
        const float* __restrict__ g, const float* __restrict__ b) {
    __shared__ float red[4];
    int tid = threadIdx.x;
    size_t row = blockIdx.x;
    float4 v = *(const float4*)(out + row * INDIM + tid * 4);
    float s = v.x + v.y + v.z + v.w;
    #pragma unroll
    for (int off = 32; off; off >>= 1) s += __shfl_xor(s, off);
    int wid = tid >> 6, lane = tid & 63;
    if (!lane) red[wid] = s;
    __syncthreads();
    float mean = (red[0] + red[1] + red[2] + red[3]) * (1.f / (float)INDIM);
    __syncthreads();
    float dx = v.x - mean, dy = v.y - mean, dz = v.z - mean, dw = v.w - mean;
    float ss = dx * dx + dy * dy + dz * dz + dw * dw;
    #pragma unroll
    for (int off = 32; off; off >>= 1) ss += __shfl_xor(ss, off);
    if (!lane) red[wid] = ss;
    __syncthreads();
    float var = (red[0] + red[1] + red[2] + red[3]) * (1.f / (float)INDIM);
    float rs = rsqrtf(var + 1e-5f);
    int c = tid * 4;
    float4 o;
    o.x = gelu_exact(dx * rs * g[c + 0] + b[c + 0]);
    o.y = gelu_exact(dy * rs * g[c + 1] + b[c + 1]);
    o.z = gelu_exact(dz * rs * g[c + 2] + b[c + 2]);
    o.w = gelu_exact(dw * rs * g[c + 3] + b[c + 3]);
    *(float4*)(out + row * INDIM + c) = o;
}

extern "C" void kernel_launch(void* const* d_in, const int* in_sizes, int n_in,
                              void* d_out, int out_size, void* d_ws, size_t ws_size,
                              hipStream_t stream) {
    const float* x     = (const float*)d_in[0];
    const float* Wp    = (const float*)d_in[1];
    const float* bp    = (const float*)d_in[2];
    const float* ln1g  = (const float*)d_in[3];
    const float* ln1b  = (const float*)d_in[4];
    const float* oW1   = (const float*)d_in[5];
    const float* ob1   = (const float*)d_in[6];
    const float* oW2   = (const float*)d_in[7];
    const float* ob2   = (const float*)d_in[8];
    const float* slots = (const float*)d_in[9];
    const float* pe    = (const float*)d_in[10];
    const float* curv  = (const float*)d_in[11];
    const float* alpha = (const float*)d_in[12];
    const float* Wo    = (const float*)d_in[13];
    const float* bo    = (const float*)d_in[14];
    const float* ln2g  = (const float*)d_in[15];
    const float* ln2b  = (const float*)d_in[16];
    float* out = (float*)d_out;
    char* ws = (char*)d_ws;

    unsigned short* qhp = (unsigned short*)(ws + OFF_QH);
    unsigned short* qlp = (unsigned short*)(ws + OFF_QL);
    float* q2p    = (float*)(ws + OFF_Q2);
    float* m2     = (float*)(ws + OFF_M2);
    float* cwv    = (float*)(ws + OFF_CW);
    float* topv   = (float*)(ws + OFF_TOPV);
    int*   topi   = (int*)  (ws + OFF_TOPI);
    float* rowmin = (float*)(ws + OFF_RMIN);
    int*   flag   = (int*)  (ws + OFF_FLAG);
    unsigned short* wot  = (unsigned short*)(ws + OFF_WOT);
    unsigned short* peh  = (unsigned short*)(ws + OFF_PEH);
    unsigned short* pel  = (unsigned short*)(ws + OFF_PEL);
    unsigned short* wpth = (unsigned short*)(ws + OFF_WPTH);
    unsigned short* wptl = (unsigned short*)(ws + OFF_WPTL);
    float* h0     = (float*)(ws + OFF_H0);
    float* rowthr = (float*)(ws + OFF_RTHR);
    unsigned short* attb = (unsigned short*)(ws + OFF_ATTB);
    float* dists  = (float*)(ws + OFF_DISTS);
    unsigned long long* cands = (unsigned long long*)(ws + OFF_CANDS);
    int*   cnt2   = (int*)  (ws + OFF_CNT2);
    unsigned short* slotb = (unsigned short*)(ws + OFF_SLOTB);

    k0_prep<<<MSLOT / 256, 256, 0, stream>>>(pe, curv, alpha, m2, cwv, peh, pel);
    k0b_cvt<<<dim3(4, 16), 256, 0, stream>>>(Wo, wot);
    k0d_wpt<<<T3, 256, 0, stream>>>(Wp, wpth, wptl);
    k0e_slotb<<<(MSLOT * HD) / 2048, 256, 0, stream>>>(slots, slotb);
    k1_mfma<<<NQ / 16, 256, 0, stream>>>(x, wpth, wptl, h0);
    k1b_ode<<<NQ / 16, 256, 0, stream>>>(h0, bp, ln1g, ln1b, oW1, ob1, oW2, ob2,
                                         qhp, qlp, q2p);
    k2a_mfma<<<dim3(NSAMP / 256, NQ / 32), 256, 0, stream>>>(
        qhp, qlp, q2p, peh, pel, m2, cwv, dists, NSAMP);
    k2b_thr<<<NQ, 256, 0, stream>>>(dists, rowthr);
    k2c_filter<<<dim3(NTIL, NQ / 256), 256, 0, stream>>>(
        qhp, qlp, q2p, peh, pel, m2, cwv, rowthr, cnt2, cands);
    k2d_select<<<NQ, 256, 0, stream>>>(cands, cnt2, topv, topi, rowmin);
    k3a_flag<<<1, 256, 0, stream>>>(rowmin, flag);
    k3_attend<<<NQ / 4, 256, 0, stream>>>(topv, topi, flag, slotb, attb);
    k4_mfma<<<dim3(INDIM / 128, NQ / 128), 256, 0, stream>>>(attb, wot, bo, out);
    k5_ln<<<NQ, 256, 0, stream>>>(out, ln2g, ln2b);
}

// Round 19
// 268.353 us; speedup vs baseline: 1.0633x; 1.0633x over previous
//
#include <hip/hip_runtime.h>
#include <math.h>

#define NQ    8192   // B*S
#define T3    48
#define INDIM 1024
#define HID   128
#define MSLOT 8192
#define HD    256
#define KBIG  48
#define KBASE 32
#define NSAMP 1024   // threshold sample = first 1024 columns
#define CAP   1024   // candidate buffer per row
#define MAXB  32     // per-block per-row LDS candidate slots

// ---- workspace layout (bytes); ws = 256 MiB ----
#define OFF_QH    ((size_t)0)           // 8192*64 bf16
#define OFF_QL    ((size_t)1048576)
#define OFF_Q2    ((size_t)2097152)
#define OFF_M2    ((size_t)2129920)
#define OFF_CW    ((size_t)2162688)
#define OFF_TOPV  ((size_t)2195456)     // 8192*48 f32
#define OFF_TOPI  ((size_t)3768320)
#define OFF_RMIN  ((size_t)5341184)
#define OFF_FLAG  ((size_t)5373952)
#define OFF_WOT   ((size_t)5374208)     // 1024*256 bf16
#define OFF_PEH   ((size_t)5898496)     // 8192*64 bf16
#define OFF_PEL   ((size_t)6947072)
#define OFF_WPTH  ((size_t)7995648)     // 48*1024 bf16
#define OFF_WPTL  ((size_t)8093952)
#define OFF_H0    ((size_t)8192256)     // 8192*48 f32
#define OFF_RTHR  ((size_t)9765120)     // 8192 f32
#define OFF_CNT   ((size_t)9797888)     // 8192 i32
#define OFF_ATTB  ((size_t)9830656)     // 8192*256 bf16 = 4,194,304
#define OFF_DISTS ((size_t)14024960)    // 8192*1024 f32 = 33,554,432
#define OFF_CANDS ((size_t)47579392)    // 8192*1024 u64 = 67,108,864
// end = 114,688,256 < 256 MiB

typedef __attribute__((ext_vector_type(8))) short short8;
typedef __attribute__((ext_vector_type(4))) float f32x4;

__device__ __forceinline__ float gelu_exact(float x) {
    return 0.5f * x * (1.0f + erff(x * 0.70710678118654752f));
}

__device__ __forceinline__ unsigned short bf16_rne(float f) {
    unsigned int x = __float_as_uint(f);
    unsigned int r = (x + 0x7fffu + ((x >> 16) & 1u)) >> 16;
    return (unsigned short)r;
}

__device__ __forceinline__ void split2(float x, unsigned short& h, unsigned short& l) {
    h = bf16_rne(x);
    l = bf16_rne(x - __uint_as_float((unsigned)h << 16));
}

// ---- K0: m2, cw, pe hi/lo bf16 (K padded to 64) ----
__global__ __launch_bounds__(256) void k0_prep(const float* __restrict__ pe,
        const float* __restrict__ curv, const float* __restrict__ alpha,
        float* __restrict__ m2, float* __restrict__ cw,
        unsigned short* __restrict__ ph, unsigned short* __restrict__ pl) {
    int m = blockIdx.x * 256 + threadIdx.x;
    float s = 0.f;
    for (int d = 0; d < T3; d++) { float v = pe[(size_t)m * T3 + d]; s += v * v; }
    m2[m] = s;
    float c = 0.f;
    for (int d = 0; d < 16; d++) { float v = curv[m * 16 + d]; c += v * v; }
    cw[m] = expf(-alpha[0] * sqrtf(c));
    int base = blockIdx.x * 256;
    for (int idx = threadIdx.x; idx < 256 * 64; idx += 256) {
        int r = idx >> 6, cc = idx & 63;
        unsigned short hi = 0, lo = 0;
        if (cc < T3) split2(pe[(size_t)(base + r) * T3 + cc], hi, lo);
        size_t o = (size_t)(base + r) * 64 + cc;
        ph[o] = hi; pl[o] = lo;
    }
}

// ---- K0b: Wo_t[n][k] = bf16(Wo[k][n]) ----
__global__ __launch_bounds__(256) void k0b_cvt(const float* __restrict__ Wo,
        unsigned short* __restrict__ Wot) {
    __shared__ float t[64][65];
    int k0 = blockIdx.x * 64;
    int n0 = blockIdx.y * 64;
    int c = threadIdx.x & 63, r4 = threadIdx.x >> 6;
    #pragma unroll
    for (int i = 0; i < 16; i++) {
        int kr = i * 4 + r4;
        t[kr][c] = Wo[(size_t)(k0 + kr) * INDIM + n0 + c];
    }
    __syncthreads();
    #pragma unroll
    for (int i = 0; i < 16; i++) {
        int nr = i * 4 + r4;
        Wot[(size_t)(n0 + nr) * HD + k0 + c] = bf16_rne(t[c][nr]);
    }
}

// ---- K0d: WpT hi/lo: wpt[n][k] = Wp[k][n] ----
__global__ __launch_bounds__(256) void k0d_wpt(const float* __restrict__ Wp,
        unsigned short* __restrict__ wph, unsigned short* __restrict__ wpl) {
    int n = blockIdx.x;
    for (int k = threadIdx.x; k < INDIM; k += 256) {
        unsigned short h, l;
        split2(Wp[(size_t)k * T3 + n], h, l);
        wph[(size_t)n * INDIM + k] = h;
        wpl[(size_t)n * INDIM + k] = l;
    }
}

// ---- K1: h0 = x @ Wp via hi/lo bf16 MFMA; 16 rows/block (512 blocks) ----
__global__ __launch_bounds__(256) void k1_mfma(const float* __restrict__ x,
        const unsigned short* __restrict__ wph, const unsigned short* __restrict__ wpl,
        float* __restrict__ h0) {
    __shared__ float part[4][16][48];
    int tid = threadIdx.x, lane = tid & 63, wv = tid >> 6;
    int r0 = blockIdx.x * 16;
    int lm = lane & 15, lk8 = (lane >> 4) * 8;
    f32x4 acc[3];
    #pragma unroll
    for (int j = 0; j < 3; j++) acc[j] = (f32x4)(0.f);
    int kw = wv * 256;
    for (int ks = 0; ks < 8; ks++) {
        int kofs = kw + ks * 32 + lk8;
        short8 ah, al, bh[3], bl[3];
        {
            const float* xp = x + (size_t)(r0 + lm) * INDIM + kofs;
            float4 xa = *(const float4*)xp;
            float4 xb = *(const float4*)(xp + 4);
            float va[8] = {xa.x, xa.y, xa.z, xa.w, xb.x, xb.y, xb.z, xb.w};
            #pragma unroll
            for (int e = 0; e < 8; e++) {
                unsigned short h, l;
                split2(va[e], h, l);
                ah[e] = (short)h; al[e] = (short)l;
            }
        }
        #pragma unroll
        for (int j = 0; j < 3; j++) {
            size_t bo = (size_t)(j * 16 + lm) * INDIM + kofs;
            bh[j] = *(const short8*)(wph + bo);
            bl[j] = *(const short8*)(wpl + bo);
        }
        #pragma unroll
        for (int j = 0; j < 3; j++) {
            f32x4 a = acc[j];
            a = __builtin_amdgcn_mfma_f32_16x16x32_bf16(ah, bh[j], a, 0, 0, 0);
            a = __builtin_amdgcn_mfma_f32_16x16x32_bf16(ah, bl[j], a, 0, 0, 0);
            a = __builtin_amdgcn_mfma_f32_16x16x32_bf16(al, bh[j], a, 0, 0, 0);
            acc[j] = a;
        }
    }
    int orow = (lane >> 4) * 4;
    #pragma unroll
    for (int j = 0; j < 3; j++)
        #pragma unroll
        for (int r = 0; r < 4; r++)
            part[wv][orow + r][j * 16 + lm] = acc[j][r];
    __syncthreads();
    for (int idx = tid; idx < 16 * 48; idx += 256) {
        int rr = idx / 48, cc = idx - rr * 48;
        float s = part[0][rr][cc] + part[1][rr][cc] + part[2][rr][cc] + part[3][rr][cc];
        h0[(size_t)(r0 + rr) * T3 + cc] = s;
    }
}

// ---- K1b: 16 rows/block: bias + LN + GELU + 2 ODE steps -> qh/ql/q2 ----
__global__ __launch_bounds__(256) void k1b_ode(const float* __restrict__ h0,
        const float* __restrict__ bp,
        const float* __restrict__ g1, const float* __restrict__ b1ln,
        const float* __restrict__ W1, const float* __restrict__ bb1,
        const float* __restrict__ W2, const float* __restrict__ bb2,
        unsigned short* __restrict__ qh, unsigned short* __restrict__ ql,
        float* __restrict__ q2out) {
    __shared__ __align__(16) float W1s[T3 * HID];
    __shared__ __align__(16) float W2s[HID * T3];
    __shared__ __align__(16) float hs[16 * T3];
    __shared__ __align__(16) float t1s[16 * 132];
    int tid = threadIdx.x;
    size_t base = (size_t)blockIdx.x * 16 * T3;
    for (int i = tid; i < 1536; i += 256) {
        *(float4*)&W1s[i * 4] = *(const float4*)&W1[i * 4];
        *(float4*)&W2s[i * 4] = *(const float4*)&W2[i * 4];
    }
    for (int idx = tid; idx < 16 * T3; idx += 256) {
        int c = idx % T3;
        t1s[idx] = bp[c] + h0[base + idx];
    }
    __syncthreads();
    {
        int r = tid >> 4, c16 = tid & 15;
        float v[3];
        float ssum = 0.f;
        #pragma unroll
        for (int i = 0; i < 3; i++) { v[i] = t1s[r * T3 + c16 * 3 + i]; ssum += v[i]; }
        #pragma unroll
        for (int off = 1; off < 16; off <<= 1) ssum += __shfl_xor(ssum, off);
        float mean = ssum * (1.f / T3);
        float vv = 0.f;
        #pragma unroll
        for (int i = 0; i < 3; i++) { v[i] -= mean; vv += v[i] * v[i]; }
        #pragma unroll
        for (int off = 1; off < 16; off <<= 1) vv += __shfl_xor(vv, off);
        float rstd = rsqrtf(vv * (1.f / T3) + 1e-5f);
        #pragma unroll
        for (int i = 0; i < 3; i++) {
            int c = c16 * 3 + i;
            hs[r * T3 + c] = gelu_exact(v[i] * rstd * g1[c] + b1ln[c]);
        }
    }
    __syncthreads();
    for (int step = 0; step < 2; step++) {
        #pragma unroll
        for (int it = 0; it < 2; it++) {
            int idx = tid + it * 256;
            int rr = idx >> 5, j4 = idx & 31;
            float4 a = *(const float4*)&bb1[j4 * 4];
            #pragma unroll 3
            for (int d4 = 0; d4 < 12; d4++) {
                float4 qv = *(const float4*)&hs[rr * T3 + d4 * 4];
                float qa[4] = {qv.x, qv.y, qv.z, qv.w};
                #pragma unroll
                for (int dd = 0; dd < 4; dd++) {
                    float4 wv = *(const float4*)&W1s[(d4 * 4 + dd) * HID + j4 * 4];
                    a.x += qa[dd] * wv.x; a.y += qa[dd] * wv.y;
                    a.z += qa[dd] * wv.z; a.w += qa[dd] * wv.w;
                }
            }
            a.x = tanhf(a.x); a.y = tanhf(a.y); a.z = tanhf(a.z); a.w = tanhf(a.w);
            *(float4*)&t1s[rr * 132 + j4 * 4] = a;
        }
        __syncthreads();
        if (tid < 192) {
            int rr = tid / 12, c4 = tid % 12;
            float4 a = *(const float4*)&bb2[c4 * 4];
            #pragma unroll 4
            for (int j4 = 0; j4 < 32; j4++) {
                float4 tv = *(const float4*)&t1s[rr * 132 + j4 * 4];
                float ta[4] = {tv.x, tv.y, tv.z, tv.w};
                #pragma unroll
                for (int jj = 0; jj < 4; jj++) {
                    float4 wv = *(const float4*)&W2s[(j4 * 4 + jj) * T3 + c4 * 4];
                    a.x += ta[jj] * wv.x; a.y += ta[jj] * wv.y;
                    a.z += ta[jj] * wv.z; a.w += ta[jj] * wv.w;
                }
            }
            float4 cur = *(const float4*)&hs[rr * T3 + c4 * 4];
            cur.x += 0.5f * a.x; cur.y += 0.5f * a.y;
            cur.z += 0.5f * a.z; cur.w += 0.5f * a.w;
            *(float4*)&hs[rr * T3 + c4 * 4] = cur;
        }
        __syncthreads();
    }
    {
        int r = tid >> 4, c16 = tid & 15;
        float sq = 0.f;
        #pragma unroll
        for (int i = 0; i < 3; i++) { float v = hs[r * T3 + c16 * 3 + i]; sq += v * v; }
        #pragma unroll
        for (int off = 1; off < 16; off <<= 1) sq += __shfl_xor(sq, off);
        if (c16 == 0) q2out[(size_t)blockIdx.x * 16 + r] = sq;
    }
    for (int idx = tid; idx < 16 * 64; idx += 256) {
        int r = idx >> 6, c = idx & 63;
        unsigned short hi = 0, lo = 0;
        if (c < T3) split2(hs[r * T3 + c], hi, lo);
        size_t o = ((size_t)blockIdx.x * 16 + r) * 64 + c;
        qh[o] = hi; ql[o] = lo;
    }
}

// ---- K2a: sample dist; 32 rows/block; pl/bq loads hoisted before barrier ----
#define PES 72
__global__ __launch_bounds__(256, 4) void k2a_mfma(
        const unsigned short* __restrict__ qh, const unsigned short* __restrict__ ql,
        const float* __restrict__ q2g,
        const unsigned short* __restrict__ ph, const unsigned short* __restrict__ pl,
        const float* __restrict__ m2, const float* __restrict__ cw,
        float* __restrict__ dist, int rowstride) {
    __shared__ __align__(16) char smem[256 * PES * 2];   // pesh 36,864B; later dt[32][260]
    __shared__ float q2s[32];
    unsigned short* pesh = (unsigned short*)smem;
    int tid = threadIdx.x, lane = tid & 63, wv = tid >> 6;
    int c0 = blockIdx.x * 256;
    int grow0 = blockIdx.y * 32;
    for (int idx = tid; idx < 2048; idx += 256) {
        int col = idx >> 3, ch = idx & 7;
        *(uint4*)&pesh[col * PES + ch * 8] = *(const uint4*)&ph[(size_t)(c0 + col) * 64 + ch * 8];
    }
    if (tid < 32) q2s[tid] = q2g[grow0 + tid];
    int lm = lane & 15, lk8 = (lane >> 4) * 8;
    int mco = wv * 64;
    // hoisted global loads: bq fragments + all pl fragments (latency hides under barrier)
    short8 bqh[2][2], bql[2][2];
    #pragma unroll
    for (int qs = 0; qs < 2; qs++)
        #pragma unroll
        for (int ks = 0; ks < 2; ks++) {
            size_t o = (size_t)(grow0 + qs * 16 + lm) * 64 + ks * 32 + lk8;
            bqh[qs][ks] = *(const short8*)&qh[o];
            bql[qs][ks] = *(const short8*)&ql[o];
        }
    short8 al0[4], al1[4];
    #pragma unroll
    for (int ms = 0; ms < 4; ms++) {
        size_t plo = (size_t)(c0 + mco + ms * 16 + lm) * 64;
        al0[ms] = *(const short8*)&pl[plo + lk8];
        al1[ms] = *(const short8*)&pl[plo + 32 + lk8];
    }
    __syncthreads();
    f32x4 acc[4][2];
    #pragma unroll
    for (int i = 0; i < 4; i++)
        #pragma unroll
        for (int j = 0; j < 2; j++) acc[i][j] = (f32x4)(0.f);
    #pragma unroll
    for (int ms = 0; ms < 4; ms++) {
        int arow = mco + ms * 16 + lm;
        short8 ah0 = *(const short8*)&pesh[arow * PES + lk8];
        short8 ah1 = *(const short8*)&pesh[arow * PES + 32 + lk8];
        #pragma unroll
        for (int qs = 0; qs < 2; qs++) {
            f32x4 a = acc[ms][qs];
            a = __builtin_amdgcn_mfma_f32_16x16x32_bf16(ah0, bqh[qs][0], a, 0, 0, 0);
            a = __builtin_amdgcn_mfma_f32_16x16x32_bf16(ah1, bqh[qs][1], a, 0, 0, 0);
            a = __builtin_amdgcn_mfma_f32_16x16x32_bf16(ah0, bql[qs][0], a, 0, 0, 0);
            a = __builtin_amdgcn_mfma_f32_16x16x32_bf16(ah1, bql[qs][1], a, 0, 0, 0);
            a = __builtin_amdgcn_mfma_f32_16x16x32_bf16(al0[ms], bqh[qs][0], a, 0, 0, 0);
            a = __builtin_amdgcn_mfma_f32_16x16x32_bf16(al1[ms], bqh[qs][1], a, 0, 0, 0);
            acc[ms][qs] = a;
        }
    }
    int mr4 = (lane >> 4) * 4;
    #pragma unroll
    for (int ms = 0; ms < 4; ms++) {
        int gm = c0 + mco + ms * 16 + mr4;
        float4 m2v = *(const float4*)&m2[gm];
        float4 cwv = *(const float4*)&cw[gm];
        float m2a[4] = {m2v.x, m2v.y, m2v.z, m2v.w};
        float cwa[4] = {cwv.x, cwv.y, cwv.z, cwv.w};
        #pragma unroll
        for (int qs = 0; qs < 2; qs++) {
            float q2 = q2s[qs * 16 + lm];
            #pragma unroll
            for (int c = 0; c < 4; c++)
                acc[ms][qs][c] = fmaxf(q2 + m2a[c] - 2.f * acc[ms][qs][c], 0.f) * cwa[c];
        }
    }
    __syncthreads();   // pesh dead -> reuse as transpose buffer
    float (*dt)[260] = (float(*)[260])smem;   // 32 x 260 f32 = 33,280B
    #pragma unroll
    for (int ms = 0; ms < 4; ms++)
        #pragma unroll
        for (int qs = 0; qs < 2; qs++) {
            float4 o;
            o.x = acc[ms][qs][0]; o.y = acc[ms][qs][1];
            o.z = acc[ms][qs][2]; o.w = acc[ms][qs][3];
            *(float4*)&dt[qs * 16 + lm][mco + ms * 16 + mr4] = o;
        }
    __syncthreads();
    #pragma unroll
    for (int i = 0; i < 8; i++) {
        int qrow = wv * 8 + i;
        float4 v = *(const float4*)&dt[qrow][lane * 4];
        *(float4*)&dist[(size_t)(grow0 + qrow) * rowstride + c0 + lane * 4] = v;
    }
}

// ---- K2b_thr: exact 48th-smallest of the NSAMP sample -> rowthr; zero cnt ----
#define NBINT 2048
#define MAXCT 512
__global__ __launch_bounds__(256) void k2b_thr(const float* __restrict__ dists,
        float* __restrict__ rowthr, int* __restrict__ cnt) {
    __shared__ unsigned int hist[NBINT];
    __shared__ unsigned long long cand[MAXCT];
    __shared__ float s_wmin[4], s_wmax[4];
    __shared__ unsigned int wsum[4];
    __shared__ unsigned int s_B, s_ncand;
    int tid = threadIdx.x, lane = tid & 63, wv = tid >> 6;
    int row = blockIdx.x;
    float4 v4 = *(const float4*)(dists + (size_t)row * NSAMP + tid * 4);
    float fv[4] = {v4.x, v4.y, v4.z, v4.w};
    float mn = fminf(fminf(fv[0], fv[1]), fminf(fv[2], fv[3]));
    float mx = fmaxf(fmaxf(fv[0], fv[1]), fmaxf(fv[2], fv[3]));
    #pragma unroll
    for (int off = 32; off; off >>= 1) {
        mn = fminf(mn, __shfl_xor(mn, off));
        mx = fmaxf(mx, __shfl_xor(mx, off));
    }
    if (lane == 0) { s_wmin[wv] = mn; s_wmax[wv] = mx; }
    __syncthreads();
    float m0 = fminf(fminf(s_wmin[0], s_wmin[1]), fminf(s_wmin[2], s_wmin[3]));
    float mX = fmaxf(fmaxf(s_wmax[0], s_wmax[1]), fmaxf(s_wmax[2], s_wmax[3]));
    float lo = m0;
    float width = fmaxf(m0 * 0.5f, 1e-3f);
    float fullw = fmaxf((mX - m0) * 1.0001f, 1e-3f) + 1e-6f;
    unsigned B = 0;
    float scale = 0.f, hiT = 0.f;
    for (int att = 0; att < 7; att++) {
        if (att == 6 || width > fullw) width = fullw;
        hiT = lo + width;
        scale = (float)NBINT / width;
        for (int i = tid; i < NBINT; i += 256) hist[i] = 0;
        __syncthreads();
        #pragma unroll
        for (int j = 0; j < 4; j++) {
            float v = fv[j];
            if (v < hiT) {
                int b = (int)((v - lo) * scale);
                b = b < NBINT - 1 ? b : NBINT - 1;
                atomicAdd(&hist[b], 1u);
            }
        }
        __syncthreads();
        unsigned hb[8];
        unsigned s = 0;
        #pragma unroll
        for (int i = 0; i < 8; i++) { hb[i] = hist[tid * 8 + i]; s += hb[i]; }
        unsigned v = s;
        #pragma unroll
        for (int off = 1; off < 64; off <<= 1) {
            unsigned o = __shfl_up(v, off);
            if (lane >= off) v += o;
        }
        if (lane == 63) wsum[wv] = v;
        __syncthreads();
        unsigned wbase = 0;
        for (int w = 0; w < wv; w++) wbase += wsum[w];
        unsigned total = wsum[0] + wsum[1] + wsum[2] + wsum[3];
        if (total >= KBIG) {
            unsigned excl = wbase + v - s;
            if (excl < KBIG && KBIG <= excl + s) {
                unsigned c = excl;
                #pragma unroll
                for (int i = 0; i < 8; i++) {
                    if (c < KBIG && KBIG <= c + hb[i]) { s_B = tid * 8 + i; break; }
                    c += hb[i];
                }
            }
            __syncthreads();
            B = s_B;
            break;
        }
        width *= 8.f;
        __syncthreads();
    }
    if (tid == 0) s_ncand = 0;
    __syncthreads();
    #pragma unroll
    for (int j = 0; j < 4; j++) {
        float v = fv[j];
        if (v < hiT) {
            int b = (int)((v - lo) * scale);
            b = b < NBINT - 1 ? b : NBINT - 1;
            if ((unsigned)b <= B) {
                unsigned n = atomicAdd(&s_ncand, 1u);
                if (n < MAXCT)
                    cand[n] = ((unsigned long long)__float_as_uint(v) << 32)
                              | (unsigned)(tid * 4 + j);
            }
        }
    }
    __syncthreads();
    int nc = (int)(s_ncand < MAXCT ? s_ncand : MAXCT);
    for (int i = tid; i < nc; i += 256) {
        unsigned long long me = cand[i];
        int rank = 0;
        for (int j = 0; j < nc; j++) rank += (cand[j] < me) ? 1 : 0;
        if (rank == KBIG - 1)
            rowthr[row] = __uint_as_float((unsigned)(me >> 32));
    }
    if (tid == 0) cnt[row] = 0;
}

// ---- K2c: full GEMM filter; 32 rows/block; pl/bq loads hoisted; aliased emission ----
__global__ __launch_bounds__(256, 4) void k2c_filter(
        const unsigned short* __restrict__ qh, const unsigned short* __restrict__ ql,
        const float* __restrict__ q2g,
        const unsigned short* __restrict__ ph, const unsigned short* __restrict__ pl,
        const float* __restrict__ m2, const float* __restrict__ cw,
        const float* __restrict__ rowthr, int* __restrict__ cnt,
        unsigned long long* __restrict__ cands) {
    __shared__ __align__(16) char smem[256 * PES * 2];   // pesh 36,864B; later lbuf 8KB
    __shared__ float q2s[32];
    __shared__ float thrs[32];
    __shared__ unsigned int lcnt[32], gbase[32];
    unsigned short* pesh = (unsigned short*)smem;
    int tid = threadIdx.x, lane = tid & 63, wv = tid >> 6;
    int c0 = blockIdx.x * 256;
    int grow0 = blockIdx.y * 32;
    for (int idx = tid; idx < 2048; idx += 256) {
        int col = idx >> 3, ch = idx & 7;
        *(uint4*)&pesh[col * PES + ch * 8] = *(const uint4*)&ph[(size_t)(c0 + col) * 64 + ch * 8];
    }
    if (tid < 32) {
        q2s[tid] = q2g[grow0 + tid];
        thrs[tid] = rowthr[grow0 + tid];
        lcnt[tid] = 0;
    }
    int lm = lane & 15, lk8 = (lane >> 4) * 8;
    int mco = wv * 64;
    // hoisted global loads (latency hides under staging barrier)
    short8 bqh[2][2], bql[2][2];
    #pragma unroll
    for (int qs = 0; qs < 2; qs++)
        #pragma unroll
        for (int ks = 0; ks < 2; ks++) {
            size_t o = (size_t)(grow0 + qs * 16 + lm) * 64 + ks * 32 + lk8;
            bqh[qs][ks] = *(const short8*)&qh[o];
            bql[qs][ks] = *(const short8*)&ql[o];
        }
    short8 al0[4], al1[4];
    #pragma unroll
    for (int ms = 0; ms < 4; ms++) {
        size_t plo = (size_t)(c0 + mco + ms * 16 + lm) * 64;
        al0[ms] = *(const short8*)&pl[plo + lk8];
        al1[ms] = *(const short8*)&pl[plo + 32 + lk8];
    }
    __syncthreads();
    f32x4 acc[4][2];
    #pragma unroll
    for (int i = 0; i < 4; i++)
        #pragma unroll
        for (int j = 0; j < 2; j++) acc[i][j] = (f32x4)(0.f);
    #pragma unroll
    for (int ms = 0; ms < 4; ms++) {
        int arow = mco + ms * 16 + lm;
        short8 ah0 = *(const short8*)&pesh[arow * PES + lk8];
        short8 ah1 = *(const short8*)&pesh[arow * PES + 32 + lk8];
        #pragma unroll
        for (int qs = 0; qs < 2; qs++) {
            f32x4 a = acc[ms][qs];
            a = __builtin_amdgcn_mfma_f32_16x16x32_bf16(ah0, bqh[qs][0], a, 0, 0, 0);
            a = __builtin_amdgcn_mfma_f32_16x16x32_bf16(ah1, bqh[qs][1], a, 0, 0, 0);
            a = __builtin_amdgcn_mfma_f32_16x16x32_bf16(ah0, bql[qs][0], a, 0, 0, 0);
            a = __builtin_amdgcn_mfma_f32_16x16x32_bf16(ah1, bql[qs][1], a, 0, 0, 0);
            a = __builtin_amdgcn_mfma_f32_16x16x32_bf16(al0[ms], bqh[qs][0], a, 0, 0, 0);
            a = __builtin_amdgcn_mfma_f32_16x16x32_bf16(al1[ms], bqh[qs][1], a, 0, 0, 0);
            acc[ms][qs] = a;
        }
    }
    // transform acc in place to dist values
    int mr4 = (lane >> 4) * 4;
    #pragma unroll
    for (int ms = 0; ms < 4; ms++) {
        int gm = c0 + mco + ms * 16 + mr4;
        float4 m2v = *(const float4*)&m2[gm];
        float4 cwv = *(const float4*)&cw[gm];
        float m2a[4] = {m2v.x, m2v.y, m2v.z, m2v.w};
        float cwa[4] = {cwv.x, cwv.y, cwv.z, cwv.w};
        #pragma unroll
        for (int qs = 0; qs < 2; qs++) {
            float q2 = q2s[qs * 16 + lm];
            #pragma unroll
            for (int c = 0; c < 4; c++)
                acc[ms][qs][c] = fmaxf(q2 + m2a[c] - 2.f * acc[ms][qs][c], 0.f) * cwa[c];
        }
    }
    __syncthreads();   // pesh dead -> alias emission buffer
    unsigned long long (*lbuf)[MAXB] = (unsigned long long(*)[MAXB])smem;  // 8KB
    #pragma unroll
    for (int ms = 0; ms < 4; ms++) {
        int gm = c0 + mco + ms * 16 + mr4;
        #pragma unroll
        for (int qs = 0; qs < 2; qs++) {
            int q = qs * 16 + lm;
            float thr = thrs[q];
            #pragma unroll
            for (int c = 0; c < 4; c++) {
                float v = acc[ms][qs][c];
                if (v <= thr) {
                    unsigned long long key =
                        ((unsigned long long)__float_as_uint(v) << 32)
                        | (unsigned)(gm + c);
                    unsigned slot = atomicAdd(&lcnt[q], 1u);
                    if (slot < MAXB) lbuf[q][slot] = key;
                    else {            // rare overflow: direct global append
                        int gs = atomicAdd(&cnt[grow0 + q], 1);
                        if (gs < CAP) cands[(size_t)(grow0 + q) * CAP + gs] = key;
                    }
                }
            }
        }
    }
    __syncthreads();
    if (tid < 32) {
        unsigned k = lcnt[tid];
        k = k < MAXB ? k : MAXB;
        lcnt[tid] = k;
        gbase[tid] = (unsigned)atomicAdd(&cnt[grow0 + tid], (int)k);
    }
    __syncthreads();
    for (int idx = tid; idx < 32 * MAXB; idx += 256) {
        int q = idx >> 5, i = idx & (MAXB - 1);
        if (i < (int)lcnt[q]) {
            unsigned b = gbase[q] + (unsigned)i;
            if (b < CAP) cands[(size_t)(grow0 + q) * CAP + b] = lbuf[q][i];
        }
    }
}

// ---- K2d: histogram prefilter -> tiny exact pairwise rank ----
#define NBIND 2048
#define FINCAP 512
__global__ __launch_bounds__(256) void k2d_select(
        const unsigned long long* __restrict__ cands, const int* __restrict__ cnt,
        float* __restrict__ topv, int* __restrict__ topi, float* __restrict__ rowmin) {
    __shared__ unsigned long long cl[CAP];       // 8KB
    __shared__ unsigned int hist[NBIND];         // 8KB
    __shared__ unsigned long long fin[FINCAP];   // 4KB
    __shared__ float s_mn[4], s_mx[4];
    __shared__ unsigned int wsum[4];
    __shared__ unsigned int s_B, s_nfin;
    int tid = threadIdx.x, lane = tid & 63, wv = tid >> 6;
    size_t row = blockIdx.x;
    int nc = cnt[row];
    nc = nc < CAP ? nc : CAP;
    float mn = 3.4e38f, mx = -3.4e38f;
    for (int i = tid; i < nc; i += 256) {
        unsigned long long k = cands[row * CAP + i];
        cl[i] = k;
        float v = __uint_as_float((unsigned)(k >> 32));
        mn = fminf(mn, v); mx = fmaxf(mx, v);
    }
    #pragma unroll
    for (int off = 32; off; off >>= 1) {
        mn = fminf(mn, __shfl_xor(mn, off));
        mx = fmaxf(mx, __shfl_xor(mx, off));
    }
    if (lane == 0) { s_mn[wv] = mn; s_mx[wv] = mx; }
    for (int i = tid; i < NBIND; i += 256) hist[i] = 0;
    if (tid == 0) s_nfin = 0;
    __syncthreads();
    float m0 = fminf(fminf(s_mn[0], s_mn[1]), fminf(s_mn[2], s_mn[3]));
    float mX = fmaxf(fmaxf(s_mx[0], s_mx[1]), fmaxf(s_mx[2], s_mx[3]));
    float width = fmaxf((mX - m0) * 1.0001f, 1e-9f) + 1e-12f;
    float scale = (float)NBIND / width;
    for (int i = tid; i < nc; i += 256) {
        float v = __uint_as_float((unsigned)(cl[i] >> 32));
        int b = (int)((v - m0) * scale);
        b = b < NBIND - 1 ? b : NBIND - 1;
        atomicAdd(&hist[b], 1u);
    }
    __syncthreads();
    {   // scan: find bin B where cumulative count reaches KBIG
        unsigned hb[8];
        unsigned s = 0;
        #pragma unroll
        for (int i = 0; i < 8; i++) { hb[i] = hist[tid * 8 + i]; s += hb[i]; }
        unsigned v = s;
        #pragma unroll
        for (int off = 1; off < 64; off <<= 1) {
            unsigned o = __shfl_up(v, off);
            if (lane >= off) v += o;
        }
        if (lane == 63) wsum[wv] = v;
        __syncthreads();
        unsigned wbase = 0;
        for (int w = 0; w < wv; w++) wbase += wsum[w];
        unsigned excl = wbase + v - s;
        unsigned tgt = (unsigned)(nc < KBIG ? nc : KBIG);
        if (excl < tgt && tgt <= excl + s) {
            unsigned c = excl;
            #pragma unroll
            for (int i = 0; i < 8; i++) {
                if (c < tgt && tgt <= c + hb[i]) { s_B = tid * 8 + i; break; }
                c += hb[i];
            }
        }
        __syncthreads();
    }
    unsigned B = s_B;
    for (int i = tid; i < nc; i += 256) {
        float v = __uint_as_float((unsigned)(cl[i] >> 32));
        int b = (int)((v - m0) * scale);
        b = b < NBIND - 1 ? b : NBIND - 1;
        if ((unsigned)b <= B) {
            unsigned n = atomicAdd(&s_nfin, 1u);
            if (n < FINCAP) fin[n] = cl[i];
        }
    }
    __syncthreads();
    int nf = (int)s_nfin;
    if (nf <= FINCAP) {
        for (int i = tid; i < nf; i += 256) {
            unsigned long long me = fin[i];
            int rank = 0;
            for (int j = 0; j < nf; j++) rank += (fin[j] < me) ? 1 : 0;
            if (rank < KBIG) {
                float v = __uint_as_float((unsigned)(me >> 32));
                topv[row * KBIG + rank] = v;
                topi[row * KBIG + rank] = (int)(me & 0xFFFFFFFFu);
                if (rank == 0) rowmin[row] = v;
            }
        }
    } else {
        for (int i = tid; i < nc; i += 256) {
            unsigned long long me = cl[i];
            int rank = 0;
            for (int j = 0; j < nc; j++) rank += (cl[j] < me) ? 1 : 0;
            if (rank < KBIG) {
                float v = __uint_as_float((unsigned)(me >> 32));
                topv[row * KBIG + rank] = v;
                topi[row * KBIG + rank] = (int)(me & 0xFFFFFFFFu);
                if (rank == 0) rowmin[row] = v;
            }
        }
    }
}

// ---- K3a: fire flag ----
__global__ __launch_bounds__(256) void k3a_flag(const float* __restrict__ rowmin,
        int* __restrict__ flag) {
    __shared__ float red[256];
    int tid = threadIdx.x;
    float s = 0.f;
    for (int j = 0; j < NQ / 256; j++) s += rowmin[tid + 256 * j];
    red[tid] = s;
    __syncthreads();
    for (int st = 128; st; st >>= 1) {
        if (tid < st) red[tid] += red[tid + st];
        __syncthreads();
    }
    if (tid == 0) {
        float top1 = red[0] / (float)NQ;
        flag[0] = (top1 < 0.7f) ? 1 : 0;
    }
}

// ---- K3: wave per row; float4 gathers; writes att as bf16 ----
__global__ __launch_bounds__(256) void k3_attend(const float* __restrict__ topv,
        const int* __restrict__ topi, const int* __restrict__ flag,
        const float* __restrict__ slots, unsigned short* __restrict__ attb) {
    int tid = threadIdx.x;
    int lane = tid & 63, wv = tid >> 6;
    size_t row = (size_t)blockIdx.x * 4 + wv;
    int kc = flag[0] ? KBIG : KBASE;
    float v0 = topv[row * KBIG];
    float ev = 0.f;
    int mi = 0;
    if (lane < KBIG) {
        float v = topv[row * KBIG + lane];
        ev = (lane < kc) ? expf(-(v - v0)) : 0.f;
        mi = topi[row * KBIG + lane];
    }
    float ssum = ev;
    #pragma unroll
    for (int off = 32; off; off >>= 1) ssum += __shfl_xor(ssum, off);
    float inv = 1.f / ssum;
    float4 acc = make_float4(0.f, 0.f, 0.f, 0.f);
    for (int k = 0; k < kc; k++) {
        float wk = __shfl(ev, k) * inv;
        int m = __shfl(mi, k);
        float4 v = *(const float4*)(slots + (size_t)m * HD + lane * 4);
        acc.x += wk * v.x; acc.y += wk * v.y;
        acc.z += wk * v.z; acc.w += wk * v.w;
    }
    ushort4 o;
    o.x = bf16_rne(acc.x); o.y = bf16_rne(acc.y);
    o.z = bf16_rne(acc.z); o.w = bf16_rne(acc.w);
    *(ushort4*)(attb + row * HD + lane * 4) = o;
}

// ---- K4: out = att(bf16) @ Wo_t(bf16)^T + bo via MFMA ----
__global__ __launch_bounds__(256) void k4_mfma(const unsigned short* __restrict__ A,
        const unsigned short* __restrict__ Bt, const float* __restrict__ bo,
        float* __restrict__ out) {
    int tid = threadIdx.x;
    int lane = tid & 63, wave = tid >> 6;
    int wm = wave >> 1, wn = wave & 1;
    int mbase = blockIdx.y * 128 + wm * 64;
    int nbase = blockIdx.x * 128 + wn * 64;
    int lm = lane & 15;
    int lk8 = (lane >> 4) * 8;
    f32x4 acc[4][4];
    #pragma unroll
    for (int i = 0; i < 4; i++)
        #pragma unroll
        for (int j = 0; j < 4; j++) acc[i][j] = (f32x4)(0.f);
    #pragma unroll 2
    for (int ks = 0; ks < 8; ks++) {
        int kofs = ks * 32 + lk8;
        short8 a[4], b[4];
        #pragma unroll
        for (int i = 0; i < 4; i++)
            a[i] = *(const short8*)(A + (size_t)(mbase + i * 16 + lm) * HD + kofs);
        #pragma unroll
        for (int j = 0; j < 4; j++)
            b[j] = *(const short8*)(Bt + (size_t)(nbase + j * 16 + lm) * HD + kofs);
        #pragma unroll
        for (int i = 0; i < 4; i++)
            #pragma unroll
            for (int j = 0; j < 4; j++)
                acc[i][j] = __builtin_amdgcn_mfma_f32_16x16x32_bf16(a[i], b[j], acc[i][j], 0, 0, 0);
    }
    int orow = (lane >> 4) * 4;
    #pragma unroll
    for (int i = 0; i < 4; i++)
        #pragma unroll
        for (int j = 0; j < 4; j++) {
            int col = nbase + j * 16 + lm;
            float bias = bo[col];
            #pragma unroll
            for (int r = 0; r < 4; r++) {
                int row = mbase + i * 16 + orow + r;
                out[(size_t)row * INDIM + col] = acc[i][j][r] + bias;
            }
        }
}

// ---- K5: LN + GELU in place ----
__global__ __launch_bounds__(256) void k5_ln(float* __restrict__ out,
        const float* __restrict__ g, const float* __restrict__ b) {
    __shared__ float red[4];
    int tid = threadIdx.x;
    size_t row = blockIdx.x;
    float4 v = *(const float4*)(out + row * INDIM + tid * 4);
    float s = v.x + v.y + v.z + v.w;
    #pragma unroll
    for (int off = 32; off; off >>= 1) s += __shfl_xor(s, off);
    int wid = tid >> 6, lane = tid & 63;
    if (!lane) red[wid] = s;
    __syncthreads();
    float mean = (red[0] + red[1] + red[2] + red[3]) * (1.f / (float)INDIM);
    __syncthreads();
    float dx = v.x - mean, dy = v.y - mean, dz = v.z - mean, dw = v.w - mean;
    float ss = dx * dx + dy * dy + dz * dz + dw * dw;
    #pragma unroll
    for (int off = 32; off; off >>= 1) ss += __shfl_xor(ss, off);
    if (!lane) red[wid] = ss;
    __syncthreads();
    float var = (red[0] + red[1] + red[2] + red[3]) * (1.f / (float)INDIM);
    float rs = rsqrtf(var + 1e-5f);
    int c = tid * 4;
    float4 o;
    o.x = gelu_exact(dx * rs * g[c + 0] + b[c + 0]);
    o.y = gelu_exact(dy * rs * g[c + 1] + b[c + 1]);
    o.z = gelu_exact(dz * rs * g[c + 2] + b[c + 2]);
    o.w = gelu_exact(dw * rs * g[c + 3] + b[c + 3]);
    *(float4*)(out + row * INDIM + c) = o;
}

extern "C" void kernel_launch(void* const* d_in, const int* in_sizes, int n_in,
                              void* d_out, int out_size, void* d_ws, size_t ws_size,
                              hipStream_t stream) {
    const float* x     = (const float*)d_in[0];
    const float* Wp    = (const float*)d_in[1];
    const float* bp    = (const float*)d_in[2];
    const float* ln1g  = (const float*)d_in[3];
    const float* ln1b  = (const float*)d_in[4];
    const float* oW1   = (const float*)d_in[5];
    const float* ob1   = (const float*)d_in[6];
    const float* oW2   = (const float*)d_in[7];
    const float* ob2   = (const float*)d_in[8];
    const float* slots = (const float*)d_in[9];
    const float* pe    = (const float*)d_in[10];
    const float* curv  = (const float*)d_in[11];
    const float* alpha = (const float*)d_in[12];
    const float* Wo    = (const float*)d_in[13];
    const float* bo    = (const float*)d_in[14];
    const float* ln2g  = (const float*)d_in[15];
    const float* ln2b  = (const float*)d_in[16];
    float* out = (float*)d_out;
    char* ws = (char*)d_ws;

    unsigned short* qhp = (unsigned short*)(ws + OFF_QH);
    unsigned short* qlp = (unsigned short*)(ws + OFF_QL);
    float* q2p    = (float*)(ws + OFF_Q2);
    float* m2     = (float*)(ws + OFF_M2);
    float* cwv    = (float*)(ws + OFF_CW);
    float* topv   = (float*)(ws + OFF_TOPV);
    int*   topi   = (int*)  (ws + OFF_TOPI);
    float* rowmin = (float*)(ws + OFF_RMIN);
    int*   flag   = (int*)  (ws + OFF_FLAG);
    unsigned short* wot  = (unsigned short*)(ws + OFF_WOT);
    unsigned short* peh  = (unsigned short*)(ws + OFF_PEH);
    unsigned short* pel  = (unsigned short*)(ws + OFF_PEL);
    unsigned short* wpth = (unsigned short*)(ws + OFF_WPTH);
    unsigned short* wptl = (unsigned short*)(ws + OFF_WPTL);
    float* h0     = (float*)(ws + OFF_H0);
    float* rowthr = (float*)(ws + OFF_RTHR);
    int*   cntp   = (int*)  (ws + OFF_CNT);
    unsigned short* attb = (unsigned short*)(ws + OFF_ATTB);
    float* dists  = (float*)(ws + OFF_DISTS);
    unsigned long long* cands = (unsigned long long*)(ws + OFF_CANDS);

    k0_prep<<<MSLOT / 256, 256, 0, stream>>>(pe, curv, alpha, m2, cwv, peh, pel);
    k0b_cvt<<<dim3(4, 16), 256, 0, stream>>>(Wo, wot);
    k0d_wpt<<<T3, 256, 0, stream>>>(Wp, wpth, wptl);
    k1_mfma<<<NQ / 16, 256, 0, stream>>>(x, wpth, wptl, h0);
    k1b_ode<<<NQ / 16, 256, 0, stream>>>(h0, bp, ln1g, ln1b, oW1, ob1, oW2, ob2,
                                         qhp, qlp, q2p);
    k2a_mfma<<<dim3(NSAMP / 256, NQ / 32), 256, 0, stream>>>(
        qhp, qlp, q2p, peh, pel, m2, cwv, dists, NSAMP);
    k2b_thr<<<NQ, 256, 0, stream>>>(dists, rowthr, cntp);
    k2c_filter<<<dim3(MSLOT / 256, NQ / 32), 256, 0, stream>>>(
        qhp, qlp, q2p, peh, pel, m2, cwv, rowthr, cntp, cands);
    k2d_select<<<NQ, 256, 0, stream>>>(cands, cntp, topv, topi, rowmin);
    k3a_flag<<<1, 256, 0, stream>>>(rowmin, flag);
    k3_attend<<<NQ / 4, 256, 0, stream>>>(topv, topi, flag, slots, attb);
    k4_mfma<<<dim3(INDIM / 128, NQ / 128), 256, 0, stream>>>(attb, wot, bo, out);
    k5_ln<<<NQ, 256, 0, stream>>>(out, ln2g, ln2b);
}